// Round 10
// baseline (62.470 us; speedup 1.0000x reference)
//
#include <hip/hip_runtime.h>

#define NQ 12
#define NL 4
typedef __attribute__((ext_vector_type(2))) float f32x2;   // (re, im)

// 128 threads t[6:0], 32 regs r[4:0]. Amp bit p = 11 - wire.
// Mapping A: i = (t<<5)|r          -> bits 11:5 = t[6:0], bits 4:0 = r
//   regs hold wires 7..11 (r bit j = wire 11-j)
// Mapping B: bit11=t6, bits10:6=r[4:0], bit5=t0, bits4:0=t[5:1]
//   regs hold wires 1..5 (r bit j = wire 5-j); wire6 = t0 (DPP); wire0 = t6.
// Layer: D_phi(A); RY w7-11 (regs); perm A->B (WAVE-LOCAL, no barrier);
//   RY w1-5 (regs); RY w6 (DPP xor1, VALU pipe); D_omega (B, w0's omega
//   excluded); exchange = [RZ(om0)*RY(th0) on wire0] + ring CNOTs + B->A,
//   one barrier'd LDS pass with GF(2)-folded read addressing.
// Layer 3: no D_omega (trailing phase), ring rho=4 folded into Z-masks,
//   exchange = RY(th0) butterfly only, final state stays in B.

__device__ __forceinline__ f32x2 cmul(f32x2 a, f32x2 b) {
    f32x2 r; r.x = a.x*b.x - a.y*b.y; r.y = a.x*b.y + a.y*b.x; return r;
}

// linear LDS bank swizzle on f32x2-slot index (involution, preserves bit0/bit11)
__host__ __device__ constexpr int SLc(int s) {
    return s ^ ((((s >> 5) ^ (s >> 9)) & 15) << 1);
}

__device__ __forceinline__ float dppx1(float x) {   // partner lane^1 (quad_perm [1,0,3,2])
    return __int_as_float(__builtin_amdgcn_mov_dpp(__float_as_int(x), 0xB1, 0xF, 0xF, true));
}

template<int P>
__device__ __forceinline__ void ry32(f32x2 (&v)[32], f32x2 g) {
    const float ct = g.x, sn = g.y;
#pragma unroll
    for (int r0 = 0; r0 < 32; ++r0) {
        if (!(r0 & (1 << P))) {
            const int r1 = r0 | (1 << P);
            const f32x2 a0 = v[r0], a1 = v[r1];
            v[r0] = ct*a0 - sn*a1;
            v[r1] = sn*a0 + ct*a1;
        }
    }
}

// v[r] *= tc * prod_j f[j]^{bit_j(r)}
__device__ __forceinline__ void diag32(f32x2 (&v)[32], f32x2 tc, const f32x2* f) {
#pragma unroll
    for (int r = 0; r < 32; ++r) v[r] = cmul(v[r], tc);
#pragma unroll
    for (int j = 0; j < 5; ++j) {
        const f32x2 fj = f[j];
#pragma unroll
        for (int r = 0; r < 32; ++r)
            if (r & (1 << j)) v[r] = cmul(v[r], fj);
    }
}

// per-reg GF(2) fold masks for ring rho (src-addr r-columns, kappa+SL folded)
template<int RHO>
__device__ __forceinline__ constexpr int GmaskF(int r) {
    int g = 0;
    if constexpr (RHO == 1) {
        if (r & 1) g ^= 0xC01; if (r & 2) g ^= 0x003; if (r & 4) g ^= 0x006;
        if (r & 8) g ^= 0x00C; if (r & 16) g ^= 0x018;
        if ((r ^ (r >> 1)) & 1) g ^= 0x41;          // j0 = r0^r1
    } else if constexpr (RHO == 2) {
        if (r & 1) g ^= 0x501; if (r & 2) g ^= 0xA02; if (r & 4) g ^= 0x005;
        if (r & 8) g ^= 0x00A; if (r & 16) g ^= 0x014;
        if ((r ^ (r >> 2)) & 1) g ^= 0x41;          // j0 = r0^r2
    } else {
        if (r & 1) g ^= 0x241; if (r & 2) g ^= 0x482; if (r & 4) g ^= 0x904;
        if (r & 8) g ^= 0x009; if (r & 16) g ^= 0x012;
        if ((r >> 3) & 1) g ^= 0x41;                // j0-part = r3 (j6 has r0, cancels)
    }
    return SLc(g);
}

template<int RHO>
__device__ __forceinline__ void exchange_ring(f32x2 (&v)[32], const f32x2* buf, int t,
    f32x2 cAa, f32x2 cBa, f32x2 cAb, f32x2 cBb)
{
    int T = 0;
    if constexpr (RHO == 1) {
        if (t & 64) T ^= 0xC00; if (t & 32) T ^= 0x600; if (t & 16) T ^= 0x300;
        if (t & 8) T ^= 0x180;  if (t & 4) T ^= 0x0C0;  if (t & 2) T ^= 0x060;
        if (t & 1) T ^= 0x030;
        if (((t >> 1) ^ (t >> 2)) & 1) T ^= 0x41;   // j6 = t1^t2
    } else if constexpr (RHO == 2) {
        if (t & 64) T ^= 0xA00; if (t & 32) T ^= 0x500; if (t & 16) T ^= 0x280;
        if (t & 8) T ^= 0x140;  if (t & 4) T ^= 0x0A0;  if (t & 2) T ^= 0x050;
        if (t & 1) T ^= 0x028;
        if (((t >> 1) ^ (t >> 3)) & 1) T ^= 0x41;   // j6 = t1^t3
    } else {
        if (t & 64) T ^= 0x900; if (t & 32) T ^= 0x480; if (t & 16) T ^= 0x240;
        if (t & 8) T ^= 0x120;  if (t & 4) T ^= 0x090;  if (t & 2) T ^= 0x048;
        if (t & 1) T ^= 0x024;
        if (((t >> 1) ^ (t >> 4)) & 1) T ^= 0x41;   // j6 t-part = t1^t4
    }
    const int TT = SLc(T);
#pragma unroll
    for (int r = 0; r < 32; ++r) {
        const int s0 = TT ^ GmaskF<RHO>(r);
        const f32x2 a  = buf[s0];
        const f32x2 bb = buf[s0 ^ 0x808];           // wire0-flipped source
        const bool hb = (r >> (RHO - 1)) & 1;       // side = t6 ^ rbit (t6 in cA*/cB*)
        const f32x2 cA = hb ? cAb : cAa;
        const f32x2 cB = hb ? cBb : cBa;
        v[r] = cmul(cA, a) + cmul(cB, bb);
    }
}

__global__ __launch_bounds__(128) void vqc_kernel(
    const float* __restrict__ x,      // (B, 12)
    const float* __restrict__ wts,    // (4, 12, 3)
    float* __restrict__ out)          // (B, 12)
{
    __shared__ alignas(16) f32x2 buf[4096];     // 32 KB state exchange
    __shared__ alignas(16) f32x2 rcs[NL * NQ];  // (cos,sin)(theta/2)
    __shared__ alignas(16) f32x2 fphi[NL][5];   // e^{i phi_{l,11-j}}
    __shared__ alignas(16) f32x2 fomg[3][5];    // e^{i omega_{l,5-j}}
    __shared__ f32x2 eo[3];                     // (cos,sin)(omega_{l,0}/2)
    __shared__ float offp[NL], offo[3];
    __shared__ float red[2][NQ];

    const int t = threadIdx.x;
    const int b = blockIdx.x;

    // ---- static tables ----
    if (t < 48) {
        float s, c; __sincosf(0.5f * wts[t*3 + 1], &s, &c);
        f32x2 tv = {c, s}; rcs[t] = tv;
    } else if (t < 68) {
        const int u = t - 48, l = u / 5, j = u % 5;
        float s, c; __sincosf(wts[(l*NQ + 11 - j)*3 + 0], &s, &c);
        f32x2 tv = {c, s}; fphi[l][j] = tv;
    } else if (t < 83) {
        const int u = t - 68, l = u / 5, j = u % 5;
        float s, c; __sincosf(wts[(l*NQ + 5 - j)*3 + 2], &s, &c);
        f32x2 tv = {c, s}; fomg[l][j] = tv;
    } else if (t < 86) {
        const int l = t - 83;
        float s, c; __sincosf(0.5f * wts[(l*NQ + 0)*3 + 2], &s, &c);
        f32x2 tv = {c, s}; eo[l] = tv;
    } else if (t < 90) {
        const int l = t - 86;
        float s = 0.f;
#pragma unroll
        for (int w = 7; w <= 11; ++w) s += wts[(l*NQ + w)*3 + 0];
        offp[l] = -0.5f * s;
    } else if (t < 93) {
        const int l = t - 90;
        float s = 0.f;
#pragma unroll
        for (int w = 1; w <= 5; ++w) s += wts[(l*NQ + w)*3 + 2];
        offo[l] = -0.5f * s;
    }

    // ---- AngleEmbedding closed form (mapping A) ----
    float cw[NQ], sw[NQ];
#pragma unroll
    for (int w = 0; w < NQ; ++w) __sincosf(0.5f * x[b*NQ + w], &sw[w], &cw[w]);
    float lm = 1.f;
#pragma unroll
    for (int k = 0; k < 7; ++k)            // t bit k <-> wire 6-k
        lm *= ((t >> k) & 1) ? sw[6-k] : cw[6-k];
    const int pt = __popc(t & 127) & 3;
    float pre[4], pim[4];
#pragma unroll
    for (int q = 0; q < 4; ++q) {          // (-i)^(pt+q)
        const int kk = (pt + q) & 3;
        pre[q] = (kk == 0) ? 1.f : ((kk == 2) ? -1.f : 0.f);
        pim[q] = (kk == 1) ? -1.f : ((kk == 3) ? 1.f : 0.f);
    }
    f32x2 v[32];
#pragma unroll
    for (int r = 0; r < 32; ++r) {         // r bit j <-> wire 11-j
        float m = lm;
        m *= (r & 1)  ? sw[11] : cw[11];
        m *= (r & 2)  ? sw[10] : cw[10];
        m *= (r & 4)  ? sw[9]  : cw[9];
        m *= (r & 8)  ? sw[8]  : cw[8];
        m *= (r & 16) ? sw[7]  : cw[7];
        const int pc = __popc(r) & 3;
        v[r].x = m * pre[pc];
        v[r].y = m * pim[pc];
    }
    __syncthreads();                        // tables ready

    // address bases (loop-invariant)
    const int wA = (t << 5) ^ (((t ^ (t >> 4)) & 15) << 1);          // SL(t<<5)
    const int jb = ((t & 64) << 5) | ((t & 1) << 5) | ((t >> 1) & 31); // B-amp base
    const int rbase = SLc(jb);                                       // perm-read base
    const int wbase = SLc(jb ^ (((t >> 1) & 1) ? 0x41 : 0));         // exch-write base
    float4* const b4 = (float4*)buf;

#pragma unroll 1
    for (int l = 0; l < NL; ++l) {
        // ---- D_phi (A): thread part wires 0-6 (t bit k <-> wire 6-k) ----
        {
            float ang = offp[l];
#pragma unroll
            for (int k = 0; k < 7; ++k) {
                const float a = 0.5f * wts[(l*NQ + (6-k))*3 + 0];
                ang += ((t >> k) & 1) ? a : -a;
            }
            float s, c; __sincosf(ang, &s, &c);
            f32x2 tc = {c, s};
            diag32(v, tc, fphi[l]);
        }
        // ---- RY wires 7..11 (A regs: wire 11-j at bit j) ----
        ry32<4>(v, rcs[l*NQ + 7]);  ry32<3>(v, rcs[l*NQ + 8]);
        ry32<2>(v, rcs[l*NQ + 9]);  ry32<1>(v, rcs[l*NQ + 10]);
        ry32<0>(v, rcs[l*NQ + 11]);

        // ---- perm A -> B (wave-local, no barrier) ----
#pragma unroll
        for (int r = 0; r < 32; r += 2) {
            const int sl = wA ^ r;   // even
            b4[sl >> 1] = make_float4(v[r].x, v[r].y, v[r+1].x, v[r+1].y);
        }
        asm volatile("s_waitcnt lgkmcnt(0)" ::: "memory");
#pragma unroll
        for (int r = 0; r < 32; ++r)
            v[r] = buf[rbase ^ SLc(r << 6)];

        // ---- RY wires 1..5 (B regs: wire 5-j at bit j) ----
        ry32<4>(v, rcs[l*NQ + 1]);  ry32<3>(v, rcs[l*NQ + 2]);
        ry32<2>(v, rcs[l*NQ + 3]);  ry32<1>(v, rcs[l*NQ + 4]);
        ry32<0>(v, rcs[l*NQ + 5]);

        // ---- RY wire 6 (t0): DPP xor1 butterfly, VALU pipe ----
        {
            const f32x2 g = rcs[l*NQ + 6];
            const float ct = g.x;
            const float sB = (t & 1) ? g.y : -g.y;
#pragma unroll
            for (int r = 0; r < 32; ++r) {
                f32x2 y; y.x = dppx1(v[r].x); y.y = dppx1(v[r].y);
                v[r] = ct * v[r] + sB * y;
            }
        }

        if (l < NL - 1) {
            // ---- D_omega (B): regs wires 1-5, thread wires 6..11 (w0 excluded) ----
            {
                float ang = offo[l];
                float a;
                a = 0.5f*wts[(l*NQ + 6)*3 + 2];  ang += (t & 1)  ? a : -a;
                a = 0.5f*wts[(l*NQ + 7)*3 + 2];  ang += (t & 32) ? a : -a;
                a = 0.5f*wts[(l*NQ + 8)*3 + 2];  ang += (t & 16) ? a : -a;
                a = 0.5f*wts[(l*NQ + 9)*3 + 2];  ang += (t & 8)  ? a : -a;
                a = 0.5f*wts[(l*NQ + 10)*3 + 2]; ang += (t & 4)  ? a : -a;
                a = 0.5f*wts[(l*NQ + 11)*3 + 2]; ang += (t & 2)  ? a : -a;
                float s, c; __sincosf(ang, &s, &c);
                f32x2 tc = {c, s};
                diag32(v, tc, fomg[l]);
            }
            // ---- exchange write (B values, kappa-layout, b128 pairs) ----
#pragma unroll
            for (int r = 0; r < 32; r += 2) {
                const int sl = wbase ^ SLc(r << 6);   // even; odd slot = ^1
                b4[sl >> 1] = make_float4(v[r].x, v[r].y, v[r+1].x, v[r+1].y);
            }
            __syncthreads();
            // ---- M = RZ(om0)*RY(th0) coefficients ----
            {
                const f32x2 g0 = rcs[l*NQ + 0];
                const float ct = g0.x, sn = g0.y;
                const f32x2 e = eo[l];
                f32x2 em = {e.x, -e.y}, ep = e;
                f32x2 cA0 = ct*em, cB0 = -sn*em;     // side 0 (wire0 of src = 0)
                f32x2 cA1 = ct*ep, cB1 =  sn*ep;     // side 1
                const bool t6 = (t >> 6) & 1;
                const f32x2 cAa = t6 ? cA1 : cA0, cBa = t6 ? cB1 : cB0;  // rbit=0
                const f32x2 cAb = t6 ? cA0 : cA1, cBb = t6 ? cB0 : cB1;  // rbit=1
                if (l == 0)      exchange_ring<1>(v, buf, t, cAa, cBa, cAb, cBb);
                else if (l == 1) exchange_ring<2>(v, buf, t, cAa, cBa, cAb, cBb);
                else             exchange_ring<3>(v, buf, t, cAa, cBa, cAb, cBb);
            }
            __syncthreads();   // reads done before next layer's perm writes
        } else {
            // ---- layer 3: RY wire0 cross-wave butterfly only ----
#pragma unroll
            for (int r = 0; r < 32; r += 2) {
                const int sl = wbase ^ SLc(r << 6);
                b4[sl >> 1] = make_float4(v[r].x, v[r].y, v[r+1].x, v[r+1].y);
            }
            __syncthreads();
            const f32x2 g0 = rcs[l*NQ + 0];
            const float ct = g0.x;
            const float sB = (t & 64) ? g0.y : -g0.y;
#pragma unroll
            for (int r = 0; r < 32; r += 2) {
                const int sl = (wbase ^ SLc(r << 6)) ^ 0x808;   // partner pair
                const float4 q = b4[sl >> 1];
                f32x2 p0 = {q.x, q.y}, p1 = {q.z, q.w};
                v[r]   = ct * v[r]   + sB * p0;
                v[r+1] = ct * v[r+1] + sB * p1;
            }
        }
    }

    // ---- <Z_w>, mapping B, ring rho=4 folded into parity masks ----
    // B holders: w0=t6 w1=r4 w2=r3 w3=r2 w4=r1 w5=r0 w6=t0 w7=t5 w8=t4 w9=t3 w10=t2 w11=t1
    float S0=0, R0=0, R1=0, R2=0, R3=0, R40=0;
#pragma unroll
    for (int r = 0; r < 32; ++r) {
        const float p = v[r].x*v[r].x + v[r].y*v[r].y;
        S0 += p;
        R0  += (r & 1) ? -p : p;
        R1  += (r & 2) ? -p : p;
        R2  += (r & 4) ? -p : p;
        R3  += (r & 8) ? -p : p;
        R40 += (((r >> 4) ^ r) & 1) ? -p : p;
    }
    const float st0 = (t & 1)  ? -1.f : 1.f;
    const float st1 = (t & 2)  ? -1.f : 1.f;
    const float st2 = (t & 4)  ? -1.f : 1.f;
    const float st3 = (t & 8)  ? -1.f : 1.f;
    const float st4 = (t & 16) ? -1.f : 1.f;
    const float st5 = (t & 32) ? -1.f : 1.f;
    const float st6 = (t & 64) ? -1.f : 1.f;

    float ev[NQ];
    ev[0] = R1*st4;      ev[1] = R0*st3;      ev[2]  = S0*st0*st2;  ev[3]  = S0*st5*st1;
    ev[4] = R1*st6;      ev[5] = R40;         ev[6]  = R3*st0;      ev[7]  = R2*st5;
    ev[8] = R1*st6*st4;  ev[9] = R40*st3;     ev[10] = R3*st0*st2;  ev[11] = R2*st5*st1;

#pragma unroll
    for (int w = 0; w < NQ; ++w)
#pragma unroll
        for (int off = 32; off; off >>= 1)
            ev[w] += __shfl_xor(ev[w], off, 64);
    if ((t & 63) == 0) {
#pragma unroll
        for (int w = 0; w < NQ; ++w) red[t >> 6][w] = ev[w];
    }
    __syncthreads();
    if (t < NQ) out[b*NQ + t] = red[0][t] + red[1][t];
}

extern "C" void kernel_launch(void* const* d_in, const int* in_sizes, int n_in,
                              void* d_out, int out_size, void* d_ws, size_t ws_size,
                              hipStream_t stream) {
    const float* x   = (const float*)d_in[0];
    const float* wts = (const float*)d_in[1];
    float* out = (float*)d_out;
    const int nb = in_sizes[0] / NQ;
    vqc_kernel<<<dim3(nb), dim3(128), 0, stream>>>(x, wts, out);
}

// Round 11
// 62.395 us; speedup vs baseline: 1.0012x; 1.0012x over previous
//
#include <hip/hip_runtime.h>

#define NQ 12
#define NL 4
typedef __attribute__((ext_vector_type(2))) float f32x2;   // (re, im)

// 128 threads t[6:0], 32 regs r[4:0]. Amp bit p = 11 - wire.
// Mapping A: i = (t<<5)|r          -> bits 11:5 = t[6:0], bits 4:0 = r
//   regs hold wires 7..11 (r bit j = wire 11-j)
// Mapping B: bit11=t6, bits10:6=r[4:0], bit5=t0, bits4:0=t[5:1]
//   regs hold wires 1..5 (r bit j = wire 5-j); wire6 = t0 (DPP); wire0 = t6.
// Layer: D_phi(A); RY w7-11 (regs); perm A->B (WAVE-LOCAL, no barrier);
//   RY w1-5 (regs); RY w6 (DPP xor1, VALU pipe); D_omega (B, w0's omega
//   excluded); exchange = [RZ(om0)*RY(th0) on wire0] + ring CNOTs + B->A,
//   one barrier'd LDS pass with GF(2)-folded read addressing.
// Layer 3: no D_omega (trailing phase), ring rho=4 folded into Z-masks,
//   exchange = RY(th0) butterfly only, final state stays in B.

__device__ __forceinline__ f32x2 cmul(f32x2 a, f32x2 b) {
    f32x2 r; r.x = a.x*b.x - a.y*b.y; r.y = a.x*b.y + a.y*b.x; return r;
}

// linear LDS bank swizzle on f32x2-slot index (involution, preserves bit0/bit11)
__host__ __device__ constexpr int SLc(int s) {
    return s ^ ((((s >> 5) ^ (s >> 9)) & 15) << 1);
}

__device__ __forceinline__ float dppx1(float x) {   // partner lane^1 (quad_perm [1,0,3,2])
    return __int_as_float(__builtin_amdgcn_mov_dpp(__float_as_int(x), 0xB1, 0xF, 0xF, true));
}

template<int P>
__device__ __forceinline__ void ry32(f32x2 (&v)[32], f32x2 g) {
    const float ct = g.x, sn = g.y;
#pragma unroll
    for (int r0 = 0; r0 < 32; ++r0) {
        if (!(r0 & (1 << P))) {
            const int r1 = r0 | (1 << P);
            const f32x2 a0 = v[r0], a1 = v[r1];
            v[r0] = ct*a0 - sn*a1;
            v[r1] = sn*a0 + ct*a1;
        }
    }
}

// v[r] *= tc * prod_j f[j]^{bit_j(r)}
__device__ __forceinline__ void diag32(f32x2 (&v)[32], f32x2 tc, const f32x2* f) {
#pragma unroll
    for (int r = 0; r < 32; ++r) v[r] = cmul(v[r], tc);
#pragma unroll
    for (int j = 0; j < 5; ++j) {
        const f32x2 fj = f[j];
#pragma unroll
        for (int r = 0; r < 32; ++r)
            if (r & (1 << j)) v[r] = cmul(v[r], fj);
    }
}

// per-reg GF(2) fold masks for ring rho (src-addr r-columns, kappa+SL folded)
template<int RHO>
__device__ __forceinline__ constexpr int GmaskF(int r) {
    int g = 0;
    if constexpr (RHO == 1) {
        if (r & 1) g ^= 0xC01; if (r & 2) g ^= 0x003; if (r & 4) g ^= 0x006;
        if (r & 8) g ^= 0x00C; if (r & 16) g ^= 0x018;
        if ((r ^ (r >> 1)) & 1) g ^= 0x41;          // j0 = r0^r1
    } else if constexpr (RHO == 2) {
        if (r & 1) g ^= 0x501; if (r & 2) g ^= 0xA02; if (r & 4) g ^= 0x005;
        if (r & 8) g ^= 0x00A; if (r & 16) g ^= 0x014;
        if ((r ^ (r >> 2)) & 1) g ^= 0x41;          // j0 = r0^r2
    } else {
        if (r & 1) g ^= 0x241; if (r & 2) g ^= 0x482; if (r & 4) g ^= 0x904;
        if (r & 8) g ^= 0x009; if (r & 16) g ^= 0x012;
        if ((r >> 3) & 1) g ^= 0x41;                // j0-part = r3 (j6 has r0, cancels)
    }
    return SLc(g);
}

template<int RHO>
__device__ __forceinline__ void exchange_ring(f32x2 (&v)[32], const f32x2* buf, int t,
    f32x2 cAa, f32x2 cBa, f32x2 cAb, f32x2 cBb)
{
    int T = 0;
    if constexpr (RHO == 1) {
        if (t & 64) T ^= 0xC00; if (t & 32) T ^= 0x600; if (t & 16) T ^= 0x300;
        if (t & 8) T ^= 0x180;  if (t & 4) T ^= 0x0C0;  if (t & 2) T ^= 0x060;
        if (t & 1) T ^= 0x030;
        if (((t >> 1) ^ (t >> 2)) & 1) T ^= 0x41;   // j6 = t1^t2
    } else if constexpr (RHO == 2) {
        if (t & 64) T ^= 0xA00; if (t & 32) T ^= 0x500; if (t & 16) T ^= 0x280;
        if (t & 8) T ^= 0x140;  if (t & 4) T ^= 0x0A0;  if (t & 2) T ^= 0x050;
        if (t & 1) T ^= 0x028;
        if (((t >> 1) ^ (t >> 3)) & 1) T ^= 0x41;   // j6 = t1^t3
    } else {
        if (t & 64) T ^= 0x900; if (t & 32) T ^= 0x480; if (t & 16) T ^= 0x240;
        if (t & 8) T ^= 0x120;  if (t & 4) T ^= 0x090;  if (t & 2) T ^= 0x048;
        if (t & 1) T ^= 0x024;
        if (((t >> 1) ^ (t >> 4)) & 1) T ^= 0x41;   // j6 t-part = t1^t4
    }
    const int TT = SLc(T);
#pragma unroll
    for (int r = 0; r < 32; ++r) {
        const int s0 = TT ^ GmaskF<RHO>(r);
        const f32x2 a  = buf[s0];
        const f32x2 bb = buf[s0 ^ 0x808];           // wire0-flipped source
        const bool hb = (r >> (RHO - 1)) & 1;       // side = t6 ^ rbit (t6 in cA*/cB*)
        const f32x2 cA = hb ? cAb : cAa;
        const f32x2 cB = hb ? cBb : cBa;
        v[r] = cmul(cA, a) + cmul(cB, bb);
    }
}

__global__ __launch_bounds__(128) void vqc_kernel(
    const float* __restrict__ x,      // (B, 12)
    const float* __restrict__ wts,    // (4, 12, 3)
    float* __restrict__ out)          // (B, 12)
{
    __shared__ alignas(16) f32x2 buf[4096];     // 32 KB state exchange
    __shared__ alignas(16) f32x2 rcs[NL * NQ];  // (cos,sin)(theta/2)
    __shared__ alignas(16) f32x2 fphi[NL][5];   // e^{i phi_{l,11-j}}
    __shared__ alignas(16) f32x2 fomg[3][5];    // e^{i omega_{l,5-j}}
    __shared__ f32x2 eo[3];                     // (cos,sin)(omega_{l,0}/2)
    __shared__ float offp[NL], offo[3];
    __shared__ float red[2][NQ];

    const int t = threadIdx.x;
    const int b = blockIdx.x;

    // ---- static tables ----
    if (t < 48) {
        float s, c; __sincosf(0.5f * wts[t*3 + 1], &s, &c);
        f32x2 tv = {c, s}; rcs[t] = tv;
    } else if (t < 68) {
        const int u = t - 48, l = u / 5, j = u % 5;
        float s, c; __sincosf(wts[(l*NQ + 11 - j)*3 + 0], &s, &c);
        f32x2 tv = {c, s}; fphi[l][j] = tv;
    } else if (t < 83) {
        const int u = t - 68, l = u / 5, j = u % 5;
        float s, c; __sincosf(wts[(l*NQ + 5 - j)*3 + 2], &s, &c);
        f32x2 tv = {c, s}; fomg[l][j] = tv;
    } else if (t < 86) {
        const int l = t - 83;
        float s, c; __sincosf(0.5f * wts[(l*NQ + 0)*3 + 2], &s, &c);
        f32x2 tv = {c, s}; eo[l] = tv;
    } else if (t < 90) {
        const int l = t - 86;
        float s = 0.f;
#pragma unroll
        for (int w = 7; w <= 11; ++w) s += wts[(l*NQ + w)*3 + 0];
        offp[l] = -0.5f * s;
    } else if (t < 93) {
        const int l = t - 90;
        float s = 0.f;
#pragma unroll
        for (int w = 1; w <= 5; ++w) s += wts[(l*NQ + w)*3 + 2];
        offo[l] = -0.5f * s;
    }

    // ---- AngleEmbedding closed form (mapping A) ----
    float cw[NQ], sw[NQ];
#pragma unroll
    for (int w = 0; w < NQ; ++w) __sincosf(0.5f * x[b*NQ + w], &sw[w], &cw[w]);
    float lm = 1.f;
#pragma unroll
    for (int k = 0; k < 7; ++k)            // t bit k <-> wire 6-k
        lm *= ((t >> k) & 1) ? sw[6-k] : cw[6-k];
    const int pt = __popc(t & 127) & 3;
    float pre[4], pim[4];
#pragma unroll
    for (int q = 0; q < 4; ++q) {          // (-i)^(pt+q)
        const int kk = (pt + q) & 3;
        pre[q] = (kk == 0) ? 1.f : ((kk == 2) ? -1.f : 0.f);
        pim[q] = (kk == 1) ? -1.f : ((kk == 3) ? 1.f : 0.f);
    }
    f32x2 v[32];
#pragma unroll
    for (int r = 0; r < 32; ++r) {         // r bit j <-> wire 11-j
        float m = lm;
        m *= (r & 1)  ? sw[11] : cw[11];
        m *= (r & 2)  ? sw[10] : cw[10];
        m *= (r & 4)  ? sw[9]  : cw[9];
        m *= (r & 8)  ? sw[8]  : cw[8];
        m *= (r & 16) ? sw[7]  : cw[7];
        const int pc = __popc(r) & 3;
        v[r].x = m * pre[pc];
        v[r].y = m * pim[pc];
    }
    __syncthreads();                        // tables ready

    // address bases (loop-invariant)
    const int wA = (t << 5) ^ (((t ^ (t >> 4)) & 15) << 1);          // SL(t<<5)
    const int jb = ((t & 64) << 5) | ((t & 1) << 5) | ((t >> 1) & 31); // B-amp base
    const int rbase = SLc(jb);                                       // perm-read base
    const int wbase = SLc(jb ^ (((t >> 1) & 1) ? 0x41 : 0));         // exch-write base
    float4* const b4 = (float4*)buf;

#pragma unroll 1
    for (int l = 0; l < NL; ++l) {
        // ---- D_phi (A): thread part wires 0-6 (t bit k <-> wire 6-k) ----
        {
            float ang = offp[l];
#pragma unroll
            for (int k = 0; k < 7; ++k) {
                const float a = 0.5f * wts[(l*NQ + (6-k))*3 + 0];
                ang += ((t >> k) & 1) ? a : -a;
            }
            float s, c; __sincosf(ang, &s, &c);
            f32x2 tc = {c, s};
            diag32(v, tc, fphi[l]);
        }
        // ---- RY wires 7..11 (A regs: wire 11-j at bit j) ----
        ry32<4>(v, rcs[l*NQ + 7]);  ry32<3>(v, rcs[l*NQ + 8]);
        ry32<2>(v, rcs[l*NQ + 9]);  ry32<1>(v, rcs[l*NQ + 10]);
        ry32<0>(v, rcs[l*NQ + 11]);

        // ---- perm A -> B (wave-local, no barrier) ----
#pragma unroll
        for (int r = 0; r < 32; r += 2) {
            const int sl = wA ^ r;   // even
            b4[sl >> 1] = make_float4(v[r].x, v[r].y, v[r+1].x, v[r+1].y);
        }
        asm volatile("s_waitcnt lgkmcnt(0)" ::: "memory");
#pragma unroll
        for (int r = 0; r < 32; ++r)
            v[r] = buf[rbase ^ SLc(r << 6)];

        // ---- RY wires 1..5 (B regs: wire 5-j at bit j) ----
        ry32<4>(v, rcs[l*NQ + 1]);  ry32<3>(v, rcs[l*NQ + 2]);
        ry32<2>(v, rcs[l*NQ + 3]);  ry32<1>(v, rcs[l*NQ + 4]);
        ry32<0>(v, rcs[l*NQ + 5]);

        // ---- RY wire 6 (t0): DPP xor1 butterfly, VALU pipe ----
        {
            const f32x2 g = rcs[l*NQ + 6];
            const float ct = g.x;
            const float sB = (t & 1) ? g.y : -g.y;
#pragma unroll
            for (int r = 0; r < 32; ++r) {
                f32x2 y; y.x = dppx1(v[r].x); y.y = dppx1(v[r].y);
                v[r] = ct * v[r] + sB * y;
            }
        }

        if (l < NL - 1) {
            // ---- D_omega (B): regs wires 1-5, thread wires 6..11 (w0 excluded) ----
            {
                float ang = offo[l];
                float a;
                a = 0.5f*wts[(l*NQ + 6)*3 + 2];  ang += (t & 1)  ? a : -a;
                a = 0.5f*wts[(l*NQ + 7)*3 + 2];  ang += (t & 32) ? a : -a;
                a = 0.5f*wts[(l*NQ + 8)*3 + 2];  ang += (t & 16) ? a : -a;
                a = 0.5f*wts[(l*NQ + 9)*3 + 2];  ang += (t & 8)  ? a : -a;
                a = 0.5f*wts[(l*NQ + 10)*3 + 2]; ang += (t & 4)  ? a : -a;
                a = 0.5f*wts[(l*NQ + 11)*3 + 2]; ang += (t & 2)  ? a : -a;
                float s, c; __sincosf(ang, &s, &c);
                f32x2 tc = {c, s};
                diag32(v, tc, fomg[l]);
            }
            // ---- exchange write (B values, kappa-layout, b128 pairs) ----
#pragma unroll
            for (int r = 0; r < 32; r += 2) {
                const int sl = wbase ^ SLc(r << 6);   // even; odd slot = ^1
                b4[sl >> 1] = make_float4(v[r].x, v[r].y, v[r+1].x, v[r+1].y);
            }
            __syncthreads();
            // ---- M = RZ(om0)*RY(th0) coefficients ----
            {
                const f32x2 g0 = rcs[l*NQ + 0];
                const float ct = g0.x, sn = g0.y;
                const f32x2 e = eo[l];
                f32x2 em = {e.x, -e.y}, ep = e;
                f32x2 cA0 = ct*em, cB0 = -sn*em;     // side 0 (wire0 of src = 0)
                f32x2 cA1 = ct*ep, cB1 =  sn*ep;     // side 1
                const bool t6 = (t >> 6) & 1;
                const f32x2 cAa = t6 ? cA1 : cA0, cBa = t6 ? cB1 : cB0;  // rbit=0
                const f32x2 cAb = t6 ? cA0 : cA1, cBb = t6 ? cB0 : cB1;  // rbit=1
                if (l == 0)      exchange_ring<1>(v, buf, t, cAa, cBa, cAb, cBb);
                else if (l == 1) exchange_ring<2>(v, buf, t, cAa, cBa, cAb, cBb);
                else             exchange_ring<3>(v, buf, t, cAa, cBa, cAb, cBb);
            }
            __syncthreads();   // reads done before next layer's perm writes
        } else {
            // ---- layer 3: RY wire0 cross-wave butterfly only ----
#pragma unroll
            for (int r = 0; r < 32; r += 2) {
                const int sl = wbase ^ SLc(r << 6);
                b4[sl >> 1] = make_float4(v[r].x, v[r].y, v[r+1].x, v[r+1].y);
            }
            __syncthreads();
            const f32x2 g0 = rcs[l*NQ + 0];
            const float ct = g0.x;
            const float sB = (t & 64) ? g0.y : -g0.y;
#pragma unroll
            for (int r = 0; r < 32; r += 2) {
                const int sl = (wbase ^ SLc(r << 6)) ^ 0x808;   // partner pair
                const float4 q = b4[sl >> 1];
                f32x2 p0 = {q.x, q.y}, p1 = {q.z, q.w};
                v[r]   = ct * v[r]   + sB * p0;
                v[r+1] = ct * v[r+1] + sB * p1;
            }
        }
    }

    // ---- <Z_w>, mapping B, ring rho=4 folded into parity masks ----
    // B holders: w0=t6 w1=r4 w2=r3 w3=r2 w4=r1 w5=r0 w6=t0 w7=t5 w8=t4 w9=t3 w10=t2 w11=t1
    float S0=0, R0=0, R1=0, R2=0, R3=0, R40=0;
#pragma unroll
    for (int r = 0; r < 32; ++r) {
        const float p = v[r].x*v[r].x + v[r].y*v[r].y;
        S0 += p;
        R0  += (r & 1) ? -p : p;
        R1  += (r & 2) ? -p : p;
        R2  += (r & 4) ? -p : p;
        R3  += (r & 8) ? -p : p;
        R40 += (((r >> 4) ^ r) & 1) ? -p : p;
    }
    const float st0 = (t & 1)  ? -1.f : 1.f;
    const float st1 = (t & 2)  ? -1.f : 1.f;
    const float st2 = (t & 4)  ? -1.f : 1.f;
    const float st3 = (t & 8)  ? -1.f : 1.f;
    const float st4 = (t & 16) ? -1.f : 1.f;
    const float st5 = (t & 32) ? -1.f : 1.f;
    const float st6 = (t & 64) ? -1.f : 1.f;

    float ev[NQ];
    ev[0] = R1*st4;      ev[1] = R0*st3;      ev[2]  = S0*st0*st2;  ev[3]  = S0*st5*st1;
    ev[4] = R1*st6;      ev[5] = R40;         ev[6]  = R3*st0;      ev[7]  = R2*st5;
    ev[8] = R1*st6*st4;  ev[9] = R40*st3;     ev[10] = R3*st0*st2;  ev[11] = R2*st5*st1;

#pragma unroll
    for (int w = 0; w < NQ; ++w)
#pragma unroll
        for (int off = 32; off; off >>= 1)
            ev[w] += __shfl_xor(ev[w], off, 64);
    if ((t & 63) == 0) {
#pragma unroll
        for (int w = 0; w < NQ; ++w) red[t >> 6][w] = ev[w];
    }
    __syncthreads();
    if (t < NQ) out[b*NQ + t] = red[0][t] + red[1][t];
}

extern "C" void kernel_launch(void* const* d_in, const int* in_sizes, int n_in,
                              void* d_out, int out_size, void* d_ws, size_t ws_size,
                              hipStream_t stream) {
    const float* x   = (const float*)d_in[0];
    const float* wts = (const float*)d_in[1];
    float* out = (float*)d_out;
    const int nb = in_sizes[0] / NQ;
    vqc_kernel<<<dim3(nb), dim3(128), 0, stream>>>(x, wts, out);
}

// Round 12
// 62.364 us; speedup vs baseline: 1.0017x; 1.0005x over previous
//
#include <hip/hip_runtime.h>

#define NQ 12
#define NL 4
typedef __attribute__((ext_vector_type(2))) float f32x2;   // (re, im)

// 128 threads t[6:0], 32 regs r[4:0]. Amp bit p = 11 - wire.
// Mapping A: i = (t<<5)|r          -> bits 11:5 = t[6:0], bits 4:0 = r
//   regs hold wires 7..11 (r bit j = wire 11-j)
// Mapping B: bit11=t6, bits10:6=r[4:0], bit5=t0, bits4:0=t[5:1]
//   regs hold wires 1..5 (r bit j = wire 5-j); wire6 = t0 (DPP); wire0 = t6.
// Layer: D_phi(A); RY w7-11 (regs); perm A->B (WAVE-LOCAL, no barrier);
//   RY w1-5 (regs); RY w6 (DPP xor1, VALU pipe); D_omega (B, w0's omega
//   excluded); exchange = [RZ(om0)*RY(th0) on wire0] + ring CNOTs + B->A,
//   one barrier'd LDS pass with GF(2)-folded read addressing.
// Layer 3: no D_omega (trailing phase), ring rho=4 folded into Z-masks,
//   exchange = RY(th0) butterfly only, final state stays in B.

__device__ __forceinline__ f32x2 cmul(f32x2 a, f32x2 b) {
    f32x2 r; r.x = a.x*b.x - a.y*b.y; r.y = a.x*b.y + a.y*b.x; return r;
}

// linear LDS bank swizzle on f32x2-slot index (involution, preserves bit0/bit11)
__host__ __device__ constexpr int SLc(int s) {
    return s ^ ((((s >> 5) ^ (s >> 9)) & 15) << 1);
}

__device__ __forceinline__ float dppx1(float x) {   // partner lane^1 (quad_perm [1,0,3,2])
    return __int_as_float(__builtin_amdgcn_mov_dpp(__float_as_int(x), 0xB1, 0xF, 0xF, true));
}

template<int P>
__device__ __forceinline__ void ry32(f32x2 (&v)[32], f32x2 g) {
    const float ct = g.x, sn = g.y;
#pragma unroll
    for (int r0 = 0; r0 < 32; ++r0) {
        if (!(r0 & (1 << P))) {
            const int r1 = r0 | (1 << P);
            const f32x2 a0 = v[r0], a1 = v[r1];
            v[r0] = ct*a0 - sn*a1;
            v[r1] = sn*a0 + ct*a1;
        }
    }
}

// v[r] *= tc * prod_j f[j]^{bit_j(r)}
__device__ __forceinline__ void diag32(f32x2 (&v)[32], f32x2 tc, const f32x2* f) {
#pragma unroll
    for (int r = 0; r < 32; ++r) v[r] = cmul(v[r], tc);
#pragma unroll
    for (int j = 0; j < 5; ++j) {
        const f32x2 fj = f[j];
#pragma unroll
        for (int r = 0; r < 32; ++r)
            if (r & (1 << j)) v[r] = cmul(v[r], fj);
    }
}

// per-reg GF(2) fold masks for ring rho (src-addr r-columns, kappa+SL folded)
template<int RHO>
__device__ __forceinline__ constexpr int GmaskF(int r) {
    int g = 0;
    if constexpr (RHO == 1) {
        if (r & 1) g ^= 0xC01; if (r & 2) g ^= 0x003; if (r & 4) g ^= 0x006;
        if (r & 8) g ^= 0x00C; if (r & 16) g ^= 0x018;
        if ((r ^ (r >> 1)) & 1) g ^= 0x41;          // j0 = r0^r1
    } else if constexpr (RHO == 2) {
        if (r & 1) g ^= 0x501; if (r & 2) g ^= 0xA02; if (r & 4) g ^= 0x005;
        if (r & 8) g ^= 0x00A; if (r & 16) g ^= 0x014;
        if ((r ^ (r >> 2)) & 1) g ^= 0x41;          // j0 = r0^r2
    } else {
        if (r & 1) g ^= 0x241; if (r & 2) g ^= 0x482; if (r & 4) g ^= 0x904;
        if (r & 8) g ^= 0x009; if (r & 16) g ^= 0x012;
        if ((r >> 3) & 1) g ^= 0x41;                // j0-part = r3 (j6 has r0, cancels)
    }
    return SLc(g);
}

template<int RHO>
__device__ __forceinline__ void exchange_ring(f32x2 (&v)[32], const f32x2* buf, int t,
    f32x2 cAa, f32x2 cBa, f32x2 cAb, f32x2 cBb)
{
    int T = 0;
    if constexpr (RHO == 1) {
        if (t & 64) T ^= 0xC00; if (t & 32) T ^= 0x600; if (t & 16) T ^= 0x300;
        if (t & 8) T ^= 0x180;  if (t & 4) T ^= 0x0C0;  if (t & 2) T ^= 0x060;
        if (t & 1) T ^= 0x030;
        if (((t >> 1) ^ (t >> 2)) & 1) T ^= 0x41;   // j6 = t1^t2
    } else if constexpr (RHO == 2) {
        if (t & 64) T ^= 0xA00; if (t & 32) T ^= 0x500; if (t & 16) T ^= 0x280;
        if (t & 8) T ^= 0x140;  if (t & 4) T ^= 0x0A0;  if (t & 2) T ^= 0x050;
        if (t & 1) T ^= 0x028;
        if (((t >> 1) ^ (t >> 3)) & 1) T ^= 0x41;   // j6 = t1^t3
    } else {
        if (t & 64) T ^= 0x900; if (t & 32) T ^= 0x480; if (t & 16) T ^= 0x240;
        if (t & 8) T ^= 0x120;  if (t & 4) T ^= 0x090;  if (t & 2) T ^= 0x048;
        if (t & 1) T ^= 0x024;
        if (((t >> 1) ^ (t >> 4)) & 1) T ^= 0x41;   // j6 t-part = t1^t4
    }
    const int TT = SLc(T);
#pragma unroll
    for (int r = 0; r < 32; ++r) {
        const int s0 = TT ^ GmaskF<RHO>(r);
        const f32x2 a  = buf[s0];
        const f32x2 bb = buf[s0 ^ 0x808];           // wire0-flipped source
        const bool hb = (r >> (RHO - 1)) & 1;       // side = t6 ^ rbit (t6 in cA*/cB*)
        const f32x2 cA = hb ? cAb : cAa;
        const f32x2 cB = hb ? cBb : cBa;
        v[r] = cmul(cA, a) + cmul(cB, bb);
    }
}

__global__ __launch_bounds__(128) void vqc_kernel(
    const float* __restrict__ x,      // (B, 12)
    const float* __restrict__ wts,    // (4, 12, 3)
    float* __restrict__ out)          // (B, 12)
{
    __shared__ alignas(16) f32x2 buf[4096];     // 32 KB state exchange
    __shared__ alignas(16) f32x2 rcs[NL * NQ];  // (cos,sin)(theta/2)
    __shared__ alignas(16) f32x2 fphi[NL][5];   // e^{i phi_{l,11-j}}
    __shared__ alignas(16) f32x2 fomg[3][5];    // e^{i omega_{l,5-j}}
    __shared__ f32x2 eo[3];                     // (cos,sin)(omega_{l,0}/2)
    __shared__ float offp[NL], offo[3];
    __shared__ float red[2][NQ];

    const int t = threadIdx.x;
    const int b = blockIdx.x;

    // ---- static tables ----
    if (t < 48) {
        float s, c; __sincosf(0.5f * wts[t*3 + 1], &s, &c);
        f32x2 tv = {c, s}; rcs[t] = tv;
    } else if (t < 68) {
        const int u = t - 48, l = u / 5, j = u % 5;
        float s, c; __sincosf(wts[(l*NQ + 11 - j)*3 + 0], &s, &c);
        f32x2 tv = {c, s}; fphi[l][j] = tv;
    } else if (t < 83) {
        const int u = t - 68, l = u / 5, j = u % 5;
        float s, c; __sincosf(wts[(l*NQ + 5 - j)*3 + 2], &s, &c);
        f32x2 tv = {c, s}; fomg[l][j] = tv;
    } else if (t < 86) {
        const int l = t - 83;
        float s, c; __sincosf(0.5f * wts[(l*NQ + 0)*3 + 2], &s, &c);
        f32x2 tv = {c, s}; eo[l] = tv;
    } else if (t < 90) {
        const int l = t - 86;
        float s = 0.f;
#pragma unroll
        for (int w = 7; w <= 11; ++w) s += wts[(l*NQ + w)*3 + 0];
        offp[l] = -0.5f * s;
    } else if (t < 93) {
        const int l = t - 90;
        float s = 0.f;
#pragma unroll
        for (int w = 1; w <= 5; ++w) s += wts[(l*NQ + w)*3 + 2];
        offo[l] = -0.5f * s;
    }

    // ---- AngleEmbedding closed form (mapping A) ----
    float cw[NQ], sw[NQ];
#pragma unroll
    for (int w = 0; w < NQ; ++w) __sincosf(0.5f * x[b*NQ + w], &sw[w], &cw[w]);
    float lm = 1.f;
#pragma unroll
    for (int k = 0; k < 7; ++k)            // t bit k <-> wire 6-k
        lm *= ((t >> k) & 1) ? sw[6-k] : cw[6-k];
    const int pt = __popc(t & 127) & 3;
    float pre[4], pim[4];
#pragma unroll
    for (int q = 0; q < 4; ++q) {          // (-i)^(pt+q)
        const int kk = (pt + q) & 3;
        pre[q] = (kk == 0) ? 1.f : ((kk == 2) ? -1.f : 0.f);
        pim[q] = (kk == 1) ? -1.f : ((kk == 3) ? 1.f : 0.f);
    }
    f32x2 v[32];
#pragma unroll
    for (int r = 0; r < 32; ++r) {         // r bit j <-> wire 11-j
        float m = lm;
        m *= (r & 1)  ? sw[11] : cw[11];
        m *= (r & 2)  ? sw[10] : cw[10];
        m *= (r & 4)  ? sw[9]  : cw[9];
        m *= (r & 8)  ? sw[8]  : cw[8];
        m *= (r & 16) ? sw[7]  : cw[7];
        const int pc = __popc(r) & 3;
        v[r].x = m * pre[pc];
        v[r].y = m * pim[pc];
    }
    __syncthreads();                        // tables ready

    // address bases (loop-invariant)
    const int wA = (t << 5) ^ (((t ^ (t >> 4)) & 15) << 1);          // SL(t<<5)
    const int jb = ((t & 64) << 5) | ((t & 1) << 5) | ((t >> 1) & 31); // B-amp base
    const int rbase = SLc(jb);                                       // perm-read base
    const int wbase = SLc(jb ^ (((t >> 1) & 1) ? 0x41 : 0));         // exch-write base
    float4* const b4 = (float4*)buf;

#pragma unroll 1
    for (int l = 0; l < NL; ++l) {
        // ---- D_phi (A): thread part wires 0-6 (t bit k <-> wire 6-k) ----
        {
            float ang = offp[l];
#pragma unroll
            for (int k = 0; k < 7; ++k) {
                const float a = 0.5f * wts[(l*NQ + (6-k))*3 + 0];
                ang += ((t >> k) & 1) ? a : -a;
            }
            float s, c; __sincosf(ang, &s, &c);
            f32x2 tc = {c, s};
            diag32(v, tc, fphi[l]);
        }
        // ---- RY wires 7..11 (A regs: wire 11-j at bit j) ----
        ry32<4>(v, rcs[l*NQ + 7]);  ry32<3>(v, rcs[l*NQ + 8]);
        ry32<2>(v, rcs[l*NQ + 9]);  ry32<1>(v, rcs[l*NQ + 10]);
        ry32<0>(v, rcs[l*NQ + 11]);

        // ---- perm A -> B (wave-local, no barrier) ----
#pragma unroll
        for (int r = 0; r < 32; r += 2) {
            const int sl = wA ^ r;   // even
            b4[sl >> 1] = make_float4(v[r].x, v[r].y, v[r+1].x, v[r+1].y);
        }
        asm volatile("s_waitcnt lgkmcnt(0)" ::: "memory");
#pragma unroll
        for (int r = 0; r < 32; ++r)
            v[r] = buf[rbase ^ SLc(r << 6)];

        // ---- RY wires 1..5 (B regs: wire 5-j at bit j) ----
        ry32<4>(v, rcs[l*NQ + 1]);  ry32<3>(v, rcs[l*NQ + 2]);
        ry32<2>(v, rcs[l*NQ + 3]);  ry32<1>(v, rcs[l*NQ + 4]);
        ry32<0>(v, rcs[l*NQ + 5]);

        // ---- RY wire 6 (t0): DPP xor1 butterfly, VALU pipe ----
        {
            const f32x2 g = rcs[l*NQ + 6];
            const float ct = g.x;
            const float sB = (t & 1) ? g.y : -g.y;
#pragma unroll
            for (int r = 0; r < 32; ++r) {
                f32x2 y; y.x = dppx1(v[r].x); y.y = dppx1(v[r].y);
                v[r] = ct * v[r] + sB * y;
            }
        }

        if (l < NL - 1) {
            // ---- D_omega (B): regs wires 1-5, thread wires 6..11 (w0 excluded) ----
            {
                float ang = offo[l];
                float a;
                a = 0.5f*wts[(l*NQ + 6)*3 + 2];  ang += (t & 1)  ? a : -a;
                a = 0.5f*wts[(l*NQ + 7)*3 + 2];  ang += (t & 32) ? a : -a;
                a = 0.5f*wts[(l*NQ + 8)*3 + 2];  ang += (t & 16) ? a : -a;
                a = 0.5f*wts[(l*NQ + 9)*3 + 2];  ang += (t & 8)  ? a : -a;
                a = 0.5f*wts[(l*NQ + 10)*3 + 2]; ang += (t & 4)  ? a : -a;
                a = 0.5f*wts[(l*NQ + 11)*3 + 2]; ang += (t & 2)  ? a : -a;
                float s, c; __sincosf(ang, &s, &c);
                f32x2 tc = {c, s};
                diag32(v, tc, fomg[l]);
            }
            // ---- exchange write (B values, kappa-layout, b128 pairs) ----
#pragma unroll
            for (int r = 0; r < 32; r += 2) {
                const int sl = wbase ^ SLc(r << 6);   // even; odd slot = ^1
                b4[sl >> 1] = make_float4(v[r].x, v[r].y, v[r+1].x, v[r+1].y);
            }
            __syncthreads();
            // ---- M = RZ(om0)*RY(th0) coefficients ----
            {
                const f32x2 g0 = rcs[l*NQ + 0];
                const float ct = g0.x, sn = g0.y;
                const f32x2 e = eo[l];
                f32x2 em = {e.x, -e.y}, ep = e;
                f32x2 cA0 = ct*em, cB0 = -sn*em;     // side 0 (wire0 of src = 0)
                f32x2 cA1 = ct*ep, cB1 =  sn*ep;     // side 1
                const bool t6 = (t >> 6) & 1;
                const f32x2 cAa = t6 ? cA1 : cA0, cBa = t6 ? cB1 : cB0;  // rbit=0
                const f32x2 cAb = t6 ? cA0 : cA1, cBb = t6 ? cB0 : cB1;  // rbit=1
                if (l == 0)      exchange_ring<1>(v, buf, t, cAa, cBa, cAb, cBb);
                else if (l == 1) exchange_ring<2>(v, buf, t, cAa, cBa, cAb, cBb);
                else             exchange_ring<3>(v, buf, t, cAa, cBa, cAb, cBb);
            }
            __syncthreads();   // reads done before next layer's perm writes
        } else {
            // ---- layer 3: RY wire0 cross-wave butterfly only ----
#pragma unroll
            for (int r = 0; r < 32; r += 2) {
                const int sl = wbase ^ SLc(r << 6);
                b4[sl >> 1] = make_float4(v[r].x, v[r].y, v[r+1].x, v[r+1].y);
            }
            __syncthreads();
            const f32x2 g0 = rcs[l*NQ + 0];
            const float ct = g0.x;
            const float sB = (t & 64) ? g0.y : -g0.y;
#pragma unroll
            for (int r = 0; r < 32; r += 2) {
                const int sl = (wbase ^ SLc(r << 6)) ^ 0x808;   // partner pair
                const float4 q = b4[sl >> 1];
                f32x2 p0 = {q.x, q.y}, p1 = {q.z, q.w};
                v[r]   = ct * v[r]   + sB * p0;
                v[r+1] = ct * v[r+1] + sB * p1;
            }
        }
    }

    // ---- <Z_w>, mapping B, ring rho=4 folded into parity masks ----
    // B holders: w0=t6 w1=r4 w2=r3 w3=r2 w4=r1 w5=r0 w6=t0 w7=t5 w8=t4 w9=t3 w10=t2 w11=t1
    float S0=0, R0=0, R1=0, R2=0, R3=0, R40=0;
#pragma unroll
    for (int r = 0; r < 32; ++r) {
        const float p = v[r].x*v[r].x + v[r].y*v[r].y;
        S0 += p;
        R0  += (r & 1) ? -p : p;
        R1  += (r & 2) ? -p : p;
        R2  += (r & 4) ? -p : p;
        R3  += (r & 8) ? -p : p;
        R40 += (((r >> 4) ^ r) & 1) ? -p : p;
    }
    const float st0 = (t & 1)  ? -1.f : 1.f;
    const float st1 = (t & 2)  ? -1.f : 1.f;
    const float st2 = (t & 4)  ? -1.f : 1.f;
    const float st3 = (t & 8)  ? -1.f : 1.f;
    const float st4 = (t & 16) ? -1.f : 1.f;
    const float st5 = (t & 32) ? -1.f : 1.f;
    const float st6 = (t & 64) ? -1.f : 1.f;

    float ev[NQ];
    ev[0] = R1*st4;      ev[1] = R0*st3;      ev[2]  = S0*st0*st2;  ev[3]  = S0*st5*st1;
    ev[4] = R1*st6;      ev[5] = R40;         ev[6]  = R3*st0;      ev[7]  = R2*st5;
    ev[8] = R1*st6*st4;  ev[9] = R40*st3;     ev[10] = R3*st0*st2;  ev[11] = R2*st5*st1;

#pragma unroll
    for (int w = 0; w < NQ; ++w)
#pragma unroll
        for (int off = 32; off; off >>= 1)
            ev[w] += __shfl_xor(ev[w], off, 64);
    if ((t & 63) == 0) {
#pragma unroll
        for (int w = 0; w < NQ; ++w) red[t >> 6][w] = ev[w];
    }
    __syncthreads();
    if (t < NQ) out[b*NQ + t] = red[0][t] + red[1][t];
}

extern "C" void kernel_launch(void* const* d_in, const int* in_sizes, int n_in,
                              void* d_out, int out_size, void* d_ws, size_t ws_size,
                              hipStream_t stream) {
    const float* x   = (const float*)d_in[0];
    const float* wts = (const float*)d_in[1];
    float* out = (float*)d_out;
    const int nb = in_sizes[0] / NQ;
    vqc_kernel<<<dim3(nb), dim3(128), 0, stream>>>(x, wts, out);
}

// Round 13
// 44.800 us; speedup vs baseline: 1.3944x; 1.3921x over previous
//
#include <hip/hip_runtime.h>

#define NQ 12
#define NL 4
typedef __attribute__((ext_vector_type(2))) float f32x2;   // (re, im)

// Amp index i[11:0], wire w <-> bit 11-w. 256 threads t[7:0], 16 regs r[3:0].
// Mapping A: i = (t<<4)|r              -> r = wires 8..11
// Mapping B: i = t[7:4]<<8|r<<4|t[3:0] -> r = wires 4..7
// Mapping C: i = (r<<8)|t              -> r = wires 0..3
// Both A and B layouts keep slot bits 11:10 = t[7:6] (the wave id), so the
// A->B permutation is WAVE-LOCAL: no __syncthreads(), only lgkmcnt(0).
// B->C and C->A move bits 11:10 through registers -> cross-wave barriers.
// Layer: D_phi (A) ; RY 8-11 (A) ; perm->B (wave-local) ; RY 4-7 (B) ;
//        perm->C ; RY 0-3 (C) ; D_omega (C) ; perm->A with ring-CNOTs folded
//        into read addressing (GF(2)-linear, verified R5/R6).
// Layer 3: D_omega dropped (trailing phase), ring folded into Z-masks.

__device__ __forceinline__ f32x2 cmul(f32x2 a, f32x2 b) {
    f32x2 r; r.x = a.x*b.x - a.y*b.y; r.y = a.x*b.y + a.y*b.x; return r;
}

// LDS swizzle on amp index: XOR higher bits into bank bits [3:1].
__device__ __forceinline__ int SW(int i) {
    return i ^ ((((i >> 4) ^ (i >> 8)) & 7) << 1);
}

template<int P>
__device__ __forceinline__ void ry16(f32x2 (&v)[16], float ct, float sn) {
#pragma unroll
    for (int r0 = 0; r0 < 16; ++r0) {
        if (!(r0 & (1 << P))) {
            const int r1 = r0 | (1 << P);
            const f32x2 a0 = v[r0], a1 = v[r1];
            v[r0] = ct*a0 - sn*a1;
            v[r1] = sn*a0 + ct*a1;
        }
    }
}

__device__ __forceinline__ void ry4grp(f32x2 (&v)[16], const f32x2* rc) {
    const f32x2 c0 = rc[0], c1 = rc[1], c2 = rc[2], c3 = rc[3];
    ry16<3>(v, c0.x, c0.y);
    ry16<2>(v, c1.x, c1.y);
    ry16<1>(v, c2.x, c2.y);
    ry16<0>(v, c3.x, c3.y);
}

// v[r] *= tc * f0^{bit3} * f1^{bit2} * f2^{bit1} * f3^{bit0}
__device__ __forceinline__ void diag_rz(f32x2 (&v)[16], f32x2 tc, const f32x2* fz) {
    const f32x2 f0 = fz[0], f1 = fz[1], f2 = fz[2], f3 = fz[3];
#pragma unroll
    for (int r = 0; r < 16; ++r) v[r] = cmul(v[r], tc);
#pragma unroll
    for (int r = 8; r < 16; ++r) v[r] = cmul(v[r], f0);
#pragma unroll
    for (int r = 0; r < 16; ++r) if (r & 4) v[r] = cmul(v[r], f1);
#pragma unroll
    for (int r = 0; r < 16; ++r) if (r & 2) v[r] = cmul(v[r], f2);
#pragma unroll
    for (int r = 0; r < 16; ++r) if (r & 1) v[r] = cmul(v[r], f3);
}

// Ring fold columns for dst reg bits (verified R5: S_rho = inverse ring map).
__device__ constexpr int foldG(int rho, int r) {
    int g = 0;
    if (rho == 1) {
        if (r & 1) g ^= 0xC01; if (r & 2) g ^= 0x003;
        if (r & 4) g ^= 0x006; if (r & 8) g ^= 0x00C;
    } else if (rho == 2) {
        if (r & 1) g ^= 0x501; if (r & 2) g ^= 0xA02;
        if (r & 4) g ^= 0x005; if (r & 8) g ^= 0x00A;
    } else {
        if (r & 1) g ^= 0x241; if (r & 2) g ^= 0x482;
        if (r & 4) g ^= 0x904; if (r & 8) g ^= 0x009;
    }
    return g;
}

template<int RHO>
__device__ __forceinline__ void readCA(f32x2 (&v)[16], const f32x2* buf, int t) {
    int F;   // thread-part columns (dst bits 4..11)
    if constexpr (RHO == 1) F = (t << 4) ^ ((t & 127) << 3) ^ ((t >> 7) << 10);
    else if constexpr (RHO == 2) F = (t << 4) ^ ((t & 255) << 2);
    else F = (t << 4) ^ ((t & 255) << 1);
#pragma unroll
    for (int r = 0; r < 16; ++r)
        v[r] = buf[SW(F ^ foldG(RHO, r))];
}

__device__ __forceinline__ void permA_write(const f32x2 (&v)[16], f32x2* buf, int t) {
    float4* b4 = (float4*)buf;
    const int base = t << 4;
#pragma unroll
    for (int r = 0; r < 16; r += 2) {
        const int a = SW(base | r);
        b4[a >> 1] = make_float4(v[r].x, v[r].y, v[r+1].x, v[r+1].y);
    }
}
__device__ __forceinline__ void permB_read(f32x2 (&v)[16], const f32x2* buf, int t) {
    const int hi = (t & 0xF0) << 4, lo = t & 15;
#pragma unroll
    for (int r = 0; r < 16; ++r) v[r] = buf[SW(hi | (r << 4) | lo)];
}
__device__ __forceinline__ void permB_write(const f32x2 (&v)[16], f32x2* buf, int t) {
    const int hi = (t & 0xF0) << 4, lo = t & 15;
#pragma unroll
    for (int r = 0; r < 16; ++r) buf[SW(hi | (r << 4) | lo)] = v[r];
}
__device__ __forceinline__ void permC_read(f32x2 (&v)[16], const f32x2* buf, int t) {
#pragma unroll
    for (int r = 0; r < 16; ++r) v[r] = buf[SW((r << 8) | t)];
}
__device__ __forceinline__ void permC_write(const f32x2 (&v)[16], f32x2* buf, int t) {
#pragma unroll
    for (int r = 0; r < 16; ++r) buf[SW((r << 8) | t)] = v[r];
}

__device__ __forceinline__ void embed(f32x2 (&v)[16], const float* __restrict__ xr, int t) {
    float cw[NQ], sw[NQ];
#pragma unroll
    for (int w = 0; w < NQ; ++w) __sincosf(0.5f * xr[w], &sw[w], &cw[w]);
    float lm = 1.f;
#pragma unroll
    for (int k = 0; k < 8; ++k) lm *= ((t >> k) & 1) ? sw[7-k] : cw[7-k];
    const int pt = __popc(t) & 3;
    float pre[4], pim[4];
#pragma unroll
    for (int q = 0; q < 4; ++q) {
        const int kk = (pt + q) & 3;      // (-i)^(pt+q)
        pre[q] = (kk == 0) ? 1.f : ((kk == 2) ? -1.f : 0.f);
        pim[q] = (kk == 1) ? -1.f : ((kk == 3) ? 1.f : 0.f);
    }
#pragma unroll
    for (int r = 0; r < 16; ++r) {
        float m = lm;
        m *= (r & 1) ? sw[11] : cw[11];
        m *= (r & 2) ? sw[10] : cw[10];
        m *= (r & 4) ? sw[9]  : cw[9];
        m *= (r & 8) ? sw[8]  : cw[8];
        const int pc = __popc(r) & 3;
        v[r].x = m * pre[pc];
        v[r].y = m * pim[pc];
    }
}

__global__ __launch_bounds__(256) void vqc_kernel(
    const float* __restrict__ x,      // (B, 12)
    const float* __restrict__ wts,    // (4, 12, 3)
    float* __restrict__ out)          // (B, 12)
{
    __shared__ alignas(16) f32x2 buf[4096];      // 32 KB exchange
    __shared__ alignas(16) f32x2 rcs[NL * NQ];   // (cos,sin)(theta/2) per wire
    __shared__ alignas(16) f32x2 rzP[NL][4];     // e^{i phi_{l,8+j}}
    __shared__ alignas(16) f32x2 rzW[3][4];      // e^{i omega_{l,j}}
    __shared__ float offs[8];                    // offP[0..3], offW[0..2]@4..6
    __shared__ float red[4][NQ];

    const int t = threadIdx.x;
    const int b = blockIdx.x;

    // ---- static tables (batch-independent) ----
    if (t < NL * NQ) {
        float s, c; __sincosf(0.5f * wts[t*3 + 1], &s, &c);
        f32x2 tv = {c, s}; rcs[t] = tv;
    } else if (t < 64) {
        const int u = t - 48, l = u >> 2, j = u & 3;
        float s, c; __sincosf(wts[(l*NQ + 8 + j)*3 + 0], &s, &c);
        f32x2 tv = {c, s}; rzP[l][j] = tv;
    } else if (t < 76) {
        const int u = t - 64, l = u >> 2, j = u & 3;
        float s, c; __sincosf(wts[(l*NQ + j)*3 + 2], &s, &c);
        f32x2 tv = {c, s}; rzW[l][j] = tv;
    } else if (t < 80) {
        const int l = t - 76;
        float s = 0.f;
#pragma unroll
        for (int j = 0; j < 4; ++j) s += wts[(l*NQ + 8 + j)*3 + 0];
        offs[l] = -0.5f * s;
    } else if (t < 83) {
        const int l = t - 80;
        float s = 0.f;
#pragma unroll
        for (int j = 0; j < 4; ++j) s += wts[(l*NQ + j)*3 + 2];
        offs[4 + l] = -0.5f * s;
    }

    // ---- AngleEmbedding closed form (mapping A) ----
    f32x2 v[16];
    embed(v, x + b*NQ, t);
    __syncthreads();                       // tables ready; buf unused yet

    // ---- 4 layers ----
#pragma unroll 1
    for (int l = 0; l < NL; ++l) {
        // D_phi thread part: wires 0..7, t bit k <-> wire 7-k (scalar loads)
        float aP = offs[l];
#pragma unroll
        for (int k = 0; k < 8; ++k)
            aP += (((t >> k) & 1) ? 0.5f : -0.5f) * wts[(l*NQ + (7-k))*3 + 0];
        float sp, cp; __sincosf(aP, &sp, &cp);
        f32x2 tcP = {cp, sp};
        diag_rz(v, tcP, rzP[l]);
        ry4grp(v, &rcs[l*NQ + 8]);         // RY wires 8..11 (A)

        // ---- perm A -> B: wave-local (slot bits 11:10 = t[7:6] both sides) ----
        permA_write(v, buf, t);
        asm volatile("s_waitcnt lgkmcnt(0)" ::: "memory");
        permB_read(v, buf, t);

        ry4grp(v, &rcs[l*NQ + 4]);         // RY wires 4..7 (B)

        // ---- perm B -> C: write own quarter (no barrier), read cross ----
        permB_write(v, buf, t);
        __syncthreads();                   // all quarters written
        permC_read(v, buf, t);

        ry4grp(v, &rcs[l*NQ + 0]);         // RY wires 0..3 (C)

        if (l == NL - 1) break;            // trailing phases + ring-3 in masks

        // D_omega thread part: wires 4..11, t bit k <-> wire 11-k
        float aW = offs[4 + l];
#pragma unroll
        for (int k = 0; k < 8; ++k)
            aW += (((t >> k) & 1) ? 0.5f : -0.5f) * wts[(l*NQ + (11-k))*3 + 2];
        float so, co; __sincosf(aW, &so, &co);
        f32x2 tcW = {co, so};
        diag_rz(v, tcW, rzW[l]);

        // ---- perm C -> A with ring fold (both cross-wave) ----
        __syncthreads();                   // all C-reads done before scatter
        permC_write(v, buf, t);
        __syncthreads();                   // all writes done before folded read
        if (l == 0)      readCA<1>(v, buf, t);
        else if (l == 1) readCA<2>(v, buf, t);
        else             readCA<3>(v, buf, t);
        __syncthreads();                   // all folded reads done before next A-write
    }

    // ---- <Z_w>, mapping C, ring-3 (rho=4) folded into parity masks ----
    float S0 = 0.f, S8 = 0.f, S4 = 0.f, S2 = 0.f, S1 = 0.f;
#pragma unroll
    for (int r = 0; r < 16; ++r) {
        const float p = v[r].x*v[r].x + v[r].y*v[r].y;
        S0 += p;
        S8 += (r & 8) ? -p : p;
        S4 += (r & 4) ? -p : p;
        S2 += (r & 2) ? -p : p;
        S1 += (r & 1) ? -p : p;
    }
    const float g88 = (__popc(t & 0x88) & 1) ? -1.f : 1.f;
    const float g44 = (__popc(t & 0x44) & 1) ? -1.f : 1.f;
    const float g22 = (__popc(t & 0x22) & 1) ? -1.f : 1.f;
    const float g11 = (__popc(t & 0x11) & 1) ? -1.f : 1.f;
    const float g80 = (t & 0x80) ? -1.f : 1.f;
    const float g40 = (t & 0x40) ? -1.f : 1.f;
    const float g20 = (t & 0x20) ? -1.f : 1.f;
    const float g10 = (t & 0x10) ? -1.f : 1.f;

    float ev[NQ];
    ev[0] = g88 * S0;  ev[1] = g44 * S0;  ev[2]  = g22 * S0;  ev[3]  = g11 * S0;
    ev[4] = g80 * S8;  ev[5] = g40 * S4;  ev[6]  = g20 * S2;  ev[7]  = g10 * S1;
    ev[8] = g88 * S8;  ev[9] = g44 * S4;  ev[10] = g22 * S2;  ev[11] = g11 * S1;

#pragma unroll
    for (int w = 0; w < NQ; ++w)
#pragma unroll
        for (int off = 32; off; off >>= 1)
            ev[w] += __shfl_xor(ev[w], off, 64);
    if ((t & 63) == 0) {
#pragma unroll
        for (int w = 0; w < NQ; ++w) red[t >> 6][w] = ev[w];
    }
    __syncthreads();
    if (t < NQ) out[b*NQ + t] = red[0][t] + red[1][t] + red[2][t] + red[3][t];
}

extern "C" void kernel_launch(void* const* d_in, const int* in_sizes, int n_in,
                              void* d_out, int out_size, void* d_ws, size_t ws_size,
                              hipStream_t stream) {
    const float* x   = (const float*)d_in[0];
    const float* wts = (const float*)d_in[1];
    float* out = (float*)d_out;
    const int nb = in_sizes[0] / NQ;
    vqc_kernel<<<dim3(nb), dim3(256), 0, stream>>>(x, wts, out);
}